// Round 1
// baseline (249.863 us; speedup 1.0000x reference)
//
#include <hip/hip_runtime.h>
#include <hip/hip_bf16.h>
#include <cstdint>
#include <cstddef>

#define NQ_ 32768
#define DM_ 256
#define DFF_ 1024
#define LNB_ 16
#define NB_ 8

typedef __attribute__((ext_vector_type(4))) float f32x4;
typedef __attribute__((ext_vector_type(8))) short s16x8;

__device__ __forceinline__ float bf2f(ushort u) {
    union { unsigned int i; float f; } c; c.i = ((unsigned int)u) << 16; return c.f;
}
__device__ __forceinline__ ushort f2bf(float f) {
    union { float f; unsigned int i; } c; c.f = f;
    unsigned int x = c.i;
    return (ushort)((x + 0x7fffu + ((x >> 16) & 1u)) >> 16); // RNE
}

// ---------------- prep kernels ----------------

__global__ __launch_bounds__(256) void prep_qk(const float* __restrict__ src, const float* __restrict__ pos,
                                               ushort* __restrict__ qkb, ushort* __restrict__ srcb) {
    int i = (blockIdx.x * 256 + threadIdx.x) * 4;
    float4 s = *(const float4*)(src + i);
    float4 p = *(const float4*)(pos + i);
    ushort4 a, b;
    a.x = f2bf(s.x + p.x); a.y = f2bf(s.y + p.y); a.z = f2bf(s.z + p.z); a.w = f2bf(s.w + p.w);
    b.x = f2bf(s.x);       b.y = f2bf(s.y);       b.z = f2bf(s.z);       b.w = f2bf(s.w);
    *(ushort4*)(qkb + i) = a;
    *(ushort4*)(srcb + i) = b;
}

// W:[K][N] f32 -> Wt:[N][K] bf16 (transposed so GEMM B-fragments are contiguous in k)
__global__ __launch_bounds__(256) void wconv(const float* __restrict__ W, ushort* __restrict__ Wt, int K, int N) {
    int i = blockIdx.x * 256 + threadIdx.x;
    if (i >= K * N) return;
    int n = i / K, k = i - n * K;
    Wt[i] = f2bf(W[k * N + n]);
}

__global__ void offs_kernel(const int* __restrict__ kbc, int* __restrict__ offs) {
    if (threadIdx.x == 0 && blockIdx.x == 0) {
        int a = 0;
        for (int b = 0; b < NB_; ++b) { offs[b] = a; a += kbc[b]; }
    }
}

// ---------------- GEMM: C_bf16[M,N] = act((A_bf16[M,K] @ Bt_bf16[N,K]^T + bias) * alpha) ----------------

__device__ __forceinline__ void gld_lds16(const ushort* g, ushort* l) {
    __builtin_amdgcn_global_load_lds((const __attribute__((address_space(1))) void*)g,
                                     (__attribute__((address_space(3))) void*)l, 16, 0, 0);
}

template <bool RELU>
__global__ __launch_bounds__(256) void gemm_kernel(const ushort* __restrict__ A, const ushort* __restrict__ Bt,
                                                   const float* __restrict__ bias, ushort* __restrict__ C,
                                                   int M, int N, int K, float alpha) {
    __shared__ __align__(16) ushort As[128 * 32];
    __shared__ __align__(16) ushort Bs[128 * 32];
    const int tid = threadIdx.x;
    const int lane = tid & 63;
    const int wave = tid >> 6;
    const int wr = wave >> 1, wc = wave & 1;
    const long m0 = (long)blockIdx.x * 128;
    const long n0 = (long)blockIdx.y * 128;

    f32x4 acc[4][4] = {};

    // staging: 512 chunks of 16B per tile (A and B each); 2 chunks/thread
    const int c0 = tid, c1 = tid + 256;
    const int ar0 = c0 >> 2, ao0 = (c0 & 3) * 8;
    const int ar1 = c1 >> 2, ao1 = (c1 & 3) * 8;
    const int la = lane & 15, lk = (lane >> 4) * 8;

    for (int kt = 0; kt < K; kt += 32) {
        gld_lds16(A + (m0 + ar0) * K + kt + ao0, As + c0 * 8);
        gld_lds16(A + (m0 + ar1) * K + kt + ao1, As + c1 * 8);
        gld_lds16(Bt + (n0 + ar0) * K + kt + ao0, Bs + c0 * 8);
        gld_lds16(Bt + (n0 + ar1) * K + kt + ao1, Bs + c1 * 8);
        __syncthreads();
        s16x8 af[4], bfr[4];
#pragma unroll
        for (int m = 0; m < 4; ++m)
            af[m] = *(const s16x8*)(As + (wr * 64 + m * 16 + la) * 32 + lk);
#pragma unroll
        for (int n = 0; n < 4; ++n)
            bfr[n] = *(const s16x8*)(Bs + (wc * 64 + n * 16 + la) * 32 + lk);
#pragma unroll
        for (int m = 0; m < 4; ++m)
#pragma unroll
            for (int n = 0; n < 4; ++n)
                acc[m][n] = __builtin_amdgcn_mfma_f32_16x16x32_bf16(af[m], bfr[n], acc[m][n], 0, 0, 0);
        __syncthreads();
    }

    // epilogue: verified C/D layout col=lane&15, row=(lane>>4)*4+j
#pragma unroll
    for (int n = 0; n < 4; ++n) {
        const long col = n0 + wc * 64 + n * 16 + la;
        const float bv = bias[col];
#pragma unroll
        for (int m = 0; m < 4; ++m) {
#pragma unroll
            for (int j = 0; j < 4; ++j) {
                const long row = m0 + wr * 64 + m * 16 + (lane >> 4) * 4 + j;
                float r = (acc[m][n][j] + bv) * alpha;
                if (RELU) r = fmaxf(r, 0.f);
                C[row * N + col] = f2bf(r);
            }
        }
    }
}

// ---------------- local attention: one wave per query ----------------
// lane = s*8 + h : head h = lane&7 (hd=32), slice s = lane>>3 covers dims 4s..4s+3 of that head.

__global__ __launch_bounds__(256) void attn_kernel(const ushort* __restrict__ Qb, const ushort* __restrict__ Kb,
                                                   const ushort* __restrict__ Vb, const int* __restrict__ ipair,
                                                   const int* __restrict__ ipb, const int* __restrict__ offs,
                                                   ushort* __restrict__ Ob) {
    const int n = (blockIdx.x * 256 + threadIdx.x) >> 6;
    const int lane = threadIdx.x & 63;
    const int eo = (lane & 7) * 32 + (lane >> 3) * 4;
    const int off = offs[ipb[n]];

    ushort4 qa = *(const ushort4*)(Qb + (size_t)n * DM_ + eo);
    float q0 = bf2f(qa.x), q1 = bf2f(qa.y), q2 = bf2f(qa.z), q3 = bf2f(qa.w);

    int gi[LNB_];
    float lg[LNB_];
#pragma unroll
    for (int j = 0; j < LNB_; ++j) {
        int ip = ipair[n * LNB_ + j];
        int g = ip >= 0 ? ip + off : 0;   // reference: invalid -> gather row 0
        gi[j] = g;
        ushort4 ka = *(const ushort4*)(Kb + (size_t)g * DM_ + eo);
        float p = q0 * bf2f(ka.x) + q1 * bf2f(ka.y) + q2 * bf2f(ka.z) + q3 * bf2f(ka.w);
        p += __shfl_xor(p, 8);
        p += __shfl_xor(p, 16);
        p += __shfl_xor(p, 32);
        lg[j] = ip >= 0 ? p : -1e9f;
    }
    float mx = lg[0];
#pragma unroll
    for (int j = 1; j < LNB_; ++j) mx = fmaxf(mx, lg[j]);
    float sum = 0.f, pw[LNB_];
#pragma unroll
    for (int j = 0; j < LNB_; ++j) { pw[j] = __expf(lg[j] - mx); sum += pw[j]; }
    const float inv = 1.f / sum;

    float a0 = 0.f, a1 = 0.f, a2 = 0.f, a3 = 0.f;
#pragma unroll
    for (int j = 0; j < LNB_; ++j) {
        ushort4 va = *(const ushort4*)(Vb + (size_t)gi[j] * DM_ + eo);
        a0 += pw[j] * bf2f(va.x); a1 += pw[j] * bf2f(va.y);
        a2 += pw[j] * bf2f(va.z); a3 += pw[j] * bf2f(va.w);
    }
    ushort4 o;
    o.x = f2bf(a0 * inv); o.y = f2bf(a1 * inv); o.z = f2bf(a2 * inv); o.w = f2bf(a3 * inv);
    *(ushort4*)(Ob + (size_t)n * DM_ + eo) = o;
}

// ---------------- LayerNorm (one wave per 256-elem row) ----------------

__global__ __launch_bounds__(256) void ln1_kernel(const float* __restrict__ a, const ushort* __restrict__ y,
                                                  const float* __restrict__ g, const float* __restrict__ be,
                                                  ushort* __restrict__ out) {
    const int row = blockIdx.x * 4 + (threadIdx.x >> 6);
    const int lane = threadIdx.x & 63;
    const int e = lane * 4;
    const size_t base = (size_t)row * DM_ + e;
    float4 av = *(const float4*)(a + base);
    ushort4 yv = *(const ushort4*)(y + base);
    float v0 = av.x + bf2f(yv.x), v1 = av.y + bf2f(yv.y), v2 = av.z + bf2f(yv.z), v3 = av.w + bf2f(yv.w);
    float s = v0 + v1 + v2 + v3;
#pragma unroll
    for (int mk = 1; mk < 64; mk <<= 1) s += __shfl_xor(s, mk);
    const float mu = s * (1.f / 256.f);
    v0 -= mu; v1 -= mu; v2 -= mu; v3 -= mu;
    float qv = v0 * v0 + v1 * v1 + v2 * v2 + v3 * v3;
#pragma unroll
    for (int mk = 1; mk < 64; mk <<= 1) qv += __shfl_xor(qv, mk);
    const float r = rsqrtf(qv * (1.f / 256.f) + 1e-5f);
    ushort4 o;
    o.x = f2bf(v0 * r * g[e] + be[e]);
    o.y = f2bf(v1 * r * g[e + 1] + be[e + 1]);
    o.z = f2bf(v2 * r * g[e + 2] + be[e + 2]);
    o.w = f2bf(v3 * r * g[e + 3] + be[e + 3]);
    *(ushort4*)(out + base) = o;
}

__global__ __launch_bounds__(256) void ln2_kernel(const ushort* __restrict__ x, const ushort* __restrict__ f,
                                                  const float* __restrict__ g, const float* __restrict__ be,
                                                  float* __restrict__ out) {
    const int row = blockIdx.x * 4 + (threadIdx.x >> 6);
    const int lane = threadIdx.x & 63;
    const int e = lane * 4;
    const size_t base = (size_t)row * DM_ + e;
    ushort4 xv = *(const ushort4*)(x + base);
    ushort4 fv = *(const ushort4*)(f + base);
    float v0 = bf2f(xv.x) + bf2f(fv.x), v1 = bf2f(xv.y) + bf2f(fv.y);
    float v2 = bf2f(xv.z) + bf2f(fv.z), v3 = bf2f(xv.w) + bf2f(fv.w);
    float s = v0 + v1 + v2 + v3;
#pragma unroll
    for (int mk = 1; mk < 64; mk <<= 1) s += __shfl_xor(s, mk);
    const float mu = s * (1.f / 256.f);
    v0 -= mu; v1 -= mu; v2 -= mu; v3 -= mu;
    float qv = v0 * v0 + v1 * v1 + v2 * v2 + v3 * v3;
#pragma unroll
    for (int mk = 1; mk < 64; mk <<= 1) qv += __shfl_xor(qv, mk);
    const float r = rsqrtf(qv * (1.f / 256.f) + 1e-5f);
    float4 o;
    o.x = v0 * r * g[e] + be[e];
    o.y = v1 * r * g[e + 1] + be[e + 1];
    o.z = v2 * r * g[e + 2] + be[e + 2];
    o.w = v3 * r * g[e + 3] + be[e + 3];
    *(float4*)(out + base) = o;
}

// ---------------- launch ----------------

extern "C" void kernel_launch(void* const* d_in, const int* in_sizes, int n_in,
                              void* d_out, int out_size, void* d_ws, size_t ws_size,
                              hipStream_t stream) {
    const float* src = (const float*)d_in[0];
    const float* pos = (const float*)d_in[1];
    const int* ipair = (const int*)d_in[2];
    const int* kbc   = (const int*)d_in[4];
    const int* ipb   = (const int*)d_in[5];
    const float* Wq = (const float*)d_in[6];  const float* bq = (const float*)d_in[7];
    const float* Wk = (const float*)d_in[8];  const float* bk = (const float*)d_in[9];
    const float* Wv = (const float*)d_in[10]; const float* bv = (const float*)d_in[11];
    const float* Wo = (const float*)d_in[12]; const float* bo = (const float*)d_in[13];
    const float* W1 = (const float*)d_in[14]; const float* b1 = (const float*)d_in[15];
    const float* W2 = (const float*)d_in[16]; const float* b2 = (const float*)d_in[17];
    const float* g1 = (const float*)d_in[18]; const float* be1 = (const float*)d_in[19];
    const float* g2 = (const float*)d_in[20]; const float* be2 = (const float*)d_in[21];

    char* ws = (char*)d_ws;
    const size_t SB = (size_t)NQ_ * DM_ * 2;   // 16 MiB per [NQ,256] bf16 buffer
    ushort* qkb  = (ushort*)(ws);              // later aliased: attn-out
    ushort* srcb = (ushort*)(ws + SB);         // later aliased: y (Wo out)
    ushort* Kb   = (ushort*)(ws + 2 * SB);
    ushort* Vb   = (ushort*)(ws + 3 * SB);
    ushort* Qb   = (ushort*)(ws + 4 * SB);     // later aliased: x (LN1 out)
    ushort* fb   = (ushort*)(ws + 5 * SB);
    ushort* hb   = (ushort*)(ws);              // FF hidden [NQ,1024] spans first 4 SB (all dead by then)
    ushort* attno = qkb;
    ushort* yb    = srcb;
    ushort* xb    = Qb;
    char* wb = ws + 6 * SB;
    ushort* WqT = (ushort*)(wb);
    ushort* WkT = (ushort*)(wb + 131072);
    ushort* WvT = (ushort*)(wb + 262144);
    ushort* WoT = (ushort*)(wb + 393216);
    ushort* W1T = (ushort*)(wb + 524288);
    ushort* W2T = (ushort*)(wb + 1048576);
    int* offs   = (int*)(wb + 1572864);

    offs_kernel<<<1, 64, 0, stream>>>(kbc, offs);
    prep_qk<<<NQ_ * DM_ / 4 / 256, 256, 0, stream>>>(src, pos, qkb, srcb);
    wconv<<<256, 256, 0, stream>>>(Wq, WqT, DM_, DM_);
    wconv<<<256, 256, 0, stream>>>(Wk, WkT, DM_, DM_);
    wconv<<<256, 256, 0, stream>>>(Wv, WvT, DM_, DM_);
    wconv<<<256, 256, 0, stream>>>(Wo, WoT, DM_, DM_);
    wconv<<<1024, 256, 0, stream>>>(W1, W1T, DM_, DFF_);
    wconv<<<1024, 256, 0, stream>>>(W2, W2T, DFF_, DM_);

    const float qscale = 0.17677669529663688f; // 1/sqrt(32), folded as (acc+bias)*alpha
    dim3 g256(NQ_ / 128, DM_ / 128);
    dim3 gff1(NQ_ / 128, DFF_ / 128);
    gemm_kernel<false><<<g256, 256, 0, stream>>>(qkb, WqT, bq, Qb, NQ_, DM_, DM_, qscale);
    gemm_kernel<false><<<g256, 256, 0, stream>>>(qkb, WkT, bk, Kb, NQ_, DM_, DM_, 1.f);
    gemm_kernel<false><<<g256, 256, 0, stream>>>(srcb, WvT, bv, Vb, NQ_, DM_, DM_, 1.f);
    attn_kernel<<<NQ_ / 4, 256, 0, stream>>>(Qb, Kb, Vb, ipair, ipb, offs, attno);
    gemm_kernel<false><<<g256, 256, 0, stream>>>(attno, WoT, bo, yb, NQ_, DM_, DM_, 1.f);
    ln1_kernel<<<NQ_ / 4, 256, 0, stream>>>(src, yb, g1, be1, xb);
    gemm_kernel<true><<<gff1, 256, 0, stream>>>(xb, W1T, b1, hb, NQ_, DFF_, DM_, 1.f);
    gemm_kernel<false><<<g256, 256, 0, stream>>>(hb, W2T, b2, fb, NQ_, DM_, DFF_, 1.f);
    ln2_kernel<<<NQ_ / 4, 256, 0, stream>>>(xb, fb, g2, be2, (float*)d_out);
}